// Round 8
// baseline (216.908 us; speedup 1.0000x reference)
//
#include <hip/hip_runtime.h>
#include <math.h>

#define BB 8
#define NN 2048
#define LL 2048
#define QQ 512
#define DD 512

typedef float f4 __attribute__((ext_vector_type(4)));

__device__ __forceinline__ void top3_insert(float v, int i, float& m0,
                                            float& m1, float& m2, int& j0,
                                            int& j1, int& j2) {
  bool gt0 = v > m0, gt1 = v > m1, gt2 = v > m2;
  float nv2 = gt1 ? m1 : (gt2 ? v : m2);
  int   ni2 = gt1 ? j1 : (gt2 ? i : j2);
  float nv1 = gt0 ? m0 : (gt1 ? v : m1);
  int   ni1 = gt0 ? j0 : (gt1 ? i : j1);
  m0 = gt0 ? v : m0;
  j0 = gt0 ? i : j0;
  m1 = nv1; j1 = ni1; m2 = nv2; j2 = ni2;
}

__device__ __forceinline__ unsigned bf16_rne(float f) {
  unsigned u = __float_as_uint(f);
  return (u + 0x7FFFu + ((u >> 16) & 1u)) >> 16;
}

// -------- Kernel A: partial top-3 (z=0..15) + emb->bf16 cvt (z=16) --------
// Top-3 part: verbatim round-7 passing structure. Grid (8 lt, 4 h, 17);
// z<16: b = z>>1, ns = z&1; wave g owns chunk ns*4+g (64 n's). Lane u
// tracks 4 l's via nt float4 loads along L; 8-deep load batching.
// z==16: 32 blocks convert the 4 f32 emb tables to bf16 into ws
// (2 MiB table -> L2-resident for kernel B), overlapped with the stream.
__global__ __launch_bounds__(256) void topk_part_kernel(
    const float* __restrict__ logits, const float* __restrict__ e0,
    const float* __restrict__ e1, const float* __restrict__ e2,
    const float* __restrict__ e3, unsigned short* __restrict__ ebf,
    f4* __restrict__ part) {
  if (blockIdx.z == 16) {  // ---- cvt slice: 32 blocks, 1M elements --------
    const float* srcs[4] = {e0, e1, e2, e3};
    const int fid = blockIdx.x + 8 * blockIdx.y;  // 0..31
    const int h   = fid >> 3;                     // 8 fids per table
    const float* src = srcs[h] + (fid & 7) * 32768;
#pragma unroll
    for (int k = 0; k < 16; ++k) {
      const int off = k * 2048 + threadIdx.x * 8;
      const float4 x = *(const float4*)(src + off);
      const float4 y = *(const float4*)(src + off + 4);
      uint4 o;
      o.x = bf16_rne(x.x) | (bf16_rne(x.y) << 16);
      o.y = bf16_rne(x.z) | (bf16_rne(x.w) << 16);
      o.z = bf16_rne(y.x) | (bf16_rne(y.y) << 16);
      o.w = bf16_rne(y.z) | (bf16_rne(y.w) << 16);
      *(uint4*)(ebf + (size_t)h * QQ * DD + (fid & 7) * 32768 + off) = o;
    }
    return;
  }

  const int u     = threadIdx.x & 63;
  const int g     = threadIdx.x >> 6;
  const int lt    = blockIdx.x;       // 0..7
  const int h     = blockIdx.y;       // 0..3
  const int b     = blockIdx.z >> 1;  // 0..7
  const int ns    = blockIdx.z & 1;   // 0..1
  const int chunk = ns * 4 + g;       // 0..7
  const int n0    = chunk * 64;
  const int l4    = lt * 256 + u * 4;

  const float* base = logits + ((size_t)(b * NN + h * QQ + n0) * LL) + l4;

  float v0[4], v1[4], v2[4];
  int   i0[4], i1[4], i2[4];
#pragma unroll
  for (int j = 0; j < 4; ++j) {
    v0[j] = v1[j] = v2[j] = -INFINITY;
    i0[j] = i1[j] = i2[j] = 0;
  }

  f4 buf[8];
  for (int t = 0; t < 8; ++t) {  // 8 batches of 8 n's, 8 loads in flight
#pragma unroll
    for (int p = 0; p < 8; ++p)
      buf[p] = __builtin_nontemporal_load(
          (const f4*)(base + (size_t)(t * 8 + p) * LL));
#pragma unroll
    for (int p = 0; p < 8; ++p) {
      const int i = n0 + t * 8 + p;
      top3_insert(buf[p][0], i, v0[0], v1[0], v2[0], i0[0], i1[0], i2[0]);
      top3_insert(buf[p][1], i, v0[1], v1[1], v2[1], i0[1], i1[1], i2[1]);
      top3_insert(buf[p][2], i, v0[2], v1[2], v2[2], i0[2], i1[2], i2[2]);
      top3_insert(buf[p][3], i, v0[3], v1[3], v2[3], i0[3], i1[3], i2[3]);
    }
  }

  // part[((b*4+h)*8 + chunk)*LL + l]
  f4* pout = part + ((size_t)((b * 4 + h) * 8 + chunk)) * LL + l4;
#pragma unroll
  for (int j = 0; j < 4; ++j) {
    unsigned int pi = (unsigned int)i0[j] | ((unsigned int)i1[j] << 9) |
                      ((unsigned int)i2[j] << 18);
    f4 rec = {v0[j], v1[j], v2[j], __uint_as_float(pi)};
    pout[j] = rec;
  }
}

// -------- Kernel B: merge + softmax + bf16 gather + transpose store -------
// 32-l tile (was 16): out-store segments widen 64B -> 128B (full lines, no
// cross-block partial-line writes). Block 512 = 8 waves; d in two 256-wide
// halves through a 32x260 LDS tile (36 KB, 4 blocks/CU). Merge phase: 128
// threads, one per (h,l). part reads non-temporal (read-once).
__global__ __launch_bounds__(512) void combine_kernel(
    const f4* __restrict__ part, const unsigned short* __restrict__ ebf,
    float* __restrict__ out) {
  const int u    = threadIdx.x & 63;
  const int w    = threadIdx.x >> 6;   // 0..7
  const int lblk = blockIdx.x * 32;
  const int b    = blockIdx.y;

  __shared__ float wt_s[4][32][3];
  __shared__ int   rid_s[4][32][3];
  __shared__ float tile[32][260];  // pad 260: rows 4 banks apart

  if (threadIdx.x < 128) {
    const int h  = threadIdx.x >> 5;
    const int il = threadIdx.x & 31;
    const int l  = lblk + il;
    const f4* pp = part + ((size_t)(b * 4 + h) * 8) * LL + l;

    float m0 = -INFINITY, m1 = -INFINITY, m2 = -INFINITY;
    int   j0 = 0, j1 = 0, j2 = 0;
#pragma unroll
    for (int c = 0; c < 8; ++c) {
      const f4 P = __builtin_nontemporal_load(pp + (size_t)c * LL);
      unsigned int pi = __float_as_uint(P[3]);
      top3_insert(P[0], pi & 511, m0, m1, m2, j0, j1, j2);
      top3_insert(P[1], (pi >> 9) & 511, m0, m1, m2, j0, j1, j2);
      top3_insert(P[2], (pi >> 18) & 511, m0, m1, m2, j0, j1, j2);
    }
    float e1 = __expf(m1 - m0), e2 = __expf(m2 - m0);
    float inv = 1.0f / (1.0f + e1 + e2);
    wt_s[h][il][0] = inv;
    wt_s[h][il][1] = e1 * inv;
    wt_s[h][il][2] = e2 * inv;
    rid_s[h][il][0] = j0;
    rid_s[h][il][1] = j1;
    rid_s[h][il][2] = j2;
  }
  __syncthreads();

  const int l0  = (threadIdx.x & 7) * 4;
  const int dof = threadIdx.x >> 3;  // 0..63
  float* outb = out + (size_t)b * DD * LL + lblk + l0;

  for (int dh = 0; dh < 2; ++dh) {
#pragma unroll
    for (int il = 0; il < 4; ++il) {
      const int ll = w * 4 + il;  // wave w owns tile rows w*4..w*4+3
      float wt[12];
      const unsigned short* rows[12];
#pragma unroll
      for (int h = 0; h < 4; ++h) {
#pragma unroll
        for (int k = 0; k < 3; ++k) {
          wt[h * 3 + k] = wt_s[h][ll][k];  // wave-uniform LDS broadcast
          rows[h * 3 + k] =
              ebf + ((size_t)h * QQ + rid_s[h][ll][k]) * DD + dh * 256;
        }
      }
      const int d = u * 4;
      float a0 = 0.f, a1 = 0.f, a2 = 0.f, a3 = 0.f;
#pragma unroll
      for (int m = 0; m < 12; ++m) {
        const uint2 e = *(const uint2*)(rows[m] + d);  // 4 bf16, L2-hit
        a0 += wt[m] * __uint_as_float(e.x << 16);
        a1 += wt[m] * __uint_as_float(e.x & 0xFFFF0000u);
        a2 += wt[m] * __uint_as_float(e.y << 16);
        a3 += wt[m] * __uint_as_float(e.y & 0xFFFF0000u);
      }
      *(float4*)&tile[ll][d] = make_float4(a0, a1, a2, a3);
    }
    __syncthreads();
#pragma unroll
    for (int dd = 0; dd < 256; dd += 64) {
      const int d = dd + dof;
      f4 r;
      r[0] = tile[l0 + 0][d];
      r[1] = tile[l0 + 1][d];
      r[2] = tile[l0 + 2][d];
      r[3] = tile[l0 + 3][d];
      // 8 lanes x 16B -> 128 B contiguous per d-row, nt store
      __builtin_nontemporal_store(r, (f4*)(outb + (size_t)(dh * 256 + d) * LL));
    }
    __syncthreads();
  }
}

extern "C" void kernel_launch(void* const* d_in, const int* in_sizes, int n_in,
                              void* d_out, int out_size, void* d_ws,
                              size_t ws_size, hipStream_t stream) {
  const float* logits = (const float*)d_in[0];
  const float* emb0   = (const float*)d_in[1];
  const float* emb1   = (const float*)d_in[2];
  const float* emb2   = (const float*)d_in[3];
  const float* emb3   = (const float*)d_in[4];
  float*       out    = (float*)d_out;
  f4*          part   = (f4*)d_ws;  // 8*4*8*2048 f4 = 8 MiB
  unsigned short* ebf = (unsigned short*)((char*)d_ws + (8u << 20));  // 2 MiB

  dim3 ga(8, 4, 17);  // z=0..15: top-3 (512 blocks); z=16: emb cvt (32)
  topk_part_kernel<<<ga, 256, 0, stream>>>(logits, emb0, emb1, emb2, emb3,
                                           ebf, part);

  dim3 gb(LL / 32, BB);  // 512 blocks, 8 waves each
  combine_kernel<<<gb, 512, 0, stream>>>(part, ebf, out);
}